// Round 4
// baseline (166.619 us; speedup 1.0000x reference)
//
#include <hip/hip_runtime.h>
#include <math.h>

#define NSAMP 32
#define SQRT3 1.7320508075688772f

typedef _Float16 half8  __attribute__((ext_vector_type(8)));
typedef float    f32x16 __attribute__((ext_vector_type(16)));

// broadcast lane L (0..31) within each 32-lane group: ds_swizzle BitMode offset = L<<5
template<int L>
__device__ __forceinline__ float bcast32(float v) {
    return __int_as_float(__builtin_amdgcn_ds_swizzle(__float_as_int(v), (L << 5)));
}

template<int K, int JJ>
struct Upd {
    static __device__ __forceinline__ void run(float* av, float lik) {
        float b = bcast32<JJ>(lik);                 // L[jj][k] of this half's loc
        av[JJ] = fmaf(-lik, b, av[JJ]);
        Upd<K, JJ + 1>::run(av, lik);
    }
};
template<int K>
struct Upd<K, NSAMP> {
    static __device__ __forceinline__ void run(float*, float) {}
};

template<int K>
struct Chol {
    static __device__ __forceinline__ void run(float* av) {
        float diag = bcast32<K>(av[K]);             // diag from lane K of this group
        float lik  = av[K] * __frsqrt_rn(diag);     // L[i][k] (valid for i>=k)
        av[K] = lik;
        Upd<K, K + 1>::run(av, lik);
        Chol<K + 1>::run(av);
    }
};
template<>
struct Chol<NSAMP> { static __device__ __forceinline__ void run(float*) {} };

__global__ __launch_bounds__(64, 6) void tmk_kernel(
    const float* __restrict__ aug,     // (32, n_loc, 31)
    const float* __restrict__ scales,  // (n_loc)
    const float* __restrict__ nug,     // (n_loc)
    const float* __restrict__ frac,    // (1)
    const int*   __restrict__ bidx,    // (n_loc)
    const float* __restrict__ thq,     // (1)
    const float* __restrict__ sigp,    // (2)
    const float* __restrict__ lens,    // (1)
    float* __restrict__ out,
    int n_loc)
{
    __shared__ float SQ[2][NSAMP];     // row norms per location (only LDS use)

    const int lane = threadIdx.x;      // one wave per block
    const int j    = lane & 31;        // sample row owned by this lane
    const int hl   = lane >> 5;        // lane half: selects k-slice (and its chol loc)
    const int kb   = 8 * hl;           // k-slice base within each 16-chunk

    const int locA = blockIdx.x * 2;
    int locB = locA + 1; if (locB >= n_loc) locB = n_loc - 1;

    // ---- uniform scalars + per-lane feature scales ----
    const float a_s   = -0.5f * __expf(thq[0]);
    const float invls = 1.0f / (__expf(lens[0]) * SQRT3);
    float scl_lo[8], scl_hi[8];
#pragma unroll
    for (int e = 0; e < 8; ++e) {
        scl_lo[e] = __expf(a_s * (float)(kb + e + 1))  * invls;   // k0 = kb+e
        scl_hi[e] = __expf(a_s * (float)(kb + e + 17)) * invls;   // k0 = 16+kb+e
    }

    const size_t srow = (size_t)n_loc * 31;
    const float fr = frac[0], sp0 = sigp[0], sp1 = sigp[1];
    float nm01[2];

    // ---- per-location: load row slice -> f16 frags -> MFMA Gram -> matern epilogue -> g store ----
#pragma unroll
    for (int h = 0; h < 2; ++h) {
        const int loc = h ? locB : locA;
        const float* rp = aug + (size_t)j * srow + (size_t)loc * 31 + 1 + kb;

        float lo[8], hi[8];
#pragma unroll
        for (int e = 0; e < 8; ++e) lo[e] = rp[e];            // k0 = kb+e      (always < 30)
#pragma unroll
        for (int e = 0; e < 8; ++e) {
            hi[e] = (16 + kb + e < 30) ? rp[16 + e] : 0.0f;   // pad k0=30,31 with 0
        }

        // nan-fix + scale + squared-norm partial + f16 convert
        half8 fLo, fHi;
        float s0 = 0.f, s1 = 0.f;
#pragma unroll
        for (int e = 0; e < 8; ++e) {
            float v = lo[e]; v = (v != v) ? 0.0f : v; v *= scl_lo[e];
            s0 = fmaf(v, v, s0);
            fLo[e] = (_Float16)v;
            float w = hi[e]; w = (w != w) ? 0.0f : w; w *= scl_hi[e];
            s1 = fmaf(w, w, s1);
            fHi[e] = (_Float16)w;
        }
        float sqp    = s0 + s1;
        float sqfull = sqp + __shfl_xor(sqp, 32, 64);   // full |x_row_j|^2 (both halves)
        if (hl == 0) SQ[h][j] = sqfull;

        // Gram: G = Xl * Xl^T via 2 MFMAs (A-frag == B-frag)
        f32x16 C = {};
        C = __builtin_amdgcn_mfma_f32_32x32x16_f16(fLo, fLo, C, 0, 0, 0);
        C = __builtin_amdgcn_mfma_f32_32x32x16_f16(fHi, fHi, C, 0, 0, 0);

        // per-location coefficient
        const float scl = scales[loc];
        const float nm  = nug[loc];
        nm01[h] = nm;
        const float sig  = __expf(sp0 + sp1 * __logf(scl));
        const float coef = fr * sig * sig / nm;
        const bool  bz   = (bidx[loc] == 0);

        // epilogue on MFMA C layout: col = j, row = (r&3)+8*(r>>2)+4*hl
        float* gout = out + (size_t)loc * 1024;
        const float* sqrow = &SQ[h][4 * hl];
#pragma unroll
        for (int r = 0; r < 16; ++r) {
            const int row0 = (r & 3) + 8 * (r >> 2);
            const bool dia = (j == row0 + 4 * hl);
            float sqi = sqrow[row0];                       // ds_read b32, broadcast per half
            float d2  = fmaf(-2.0f, C[r], sqi + sqfull);
            d2 = dia ? 0.0f : fmaxf(d2, 0.0f);             // exact-0 diagonal + clip
            float s3d = __fsqrt_rn(3.0f * d2);
            float nl  = (1.0f + s3d) * __expf(-s3d);
            float dg  = dia ? 1.0f : 0.0f;
            float gv  = fmaf(coef, nl, dg);
            if (bz) gv = dg;
            gout[(row0 + 4 * hl) * 32 + j] = gv;           // 2x128B rows per store instr
        }
    }

    // ---- read own chol row back through L2 (stores must be visible first) ----
    asm volatile("s_waitcnt vmcnt(0)" ::: "memory");
    const int locS = hl ? locB : locA;
    const size_t gbase = (size_t)locS * 1024;
    const float* grow = out + gbase + (size_t)j * 32;
    float av[32];
#pragma unroll
    for (int c = 0; c < 8; ++c) {
        float4 v = *reinterpret_cast<const float4*>(grow + 4 * c);   // 16B-aligned, L2-hit
        av[4 * c + 0] = v.x; av[4 * c + 1] = v.y;
        av[4 * c + 2] = v.z; av[4 * c + 3] = v.w;
    }

    // ---- register Cholesky: lane j = row j of its half's loc ----
    Chol<0>::run(av);

    // ---- masked L row store ----
    float* lrow = out + (size_t)n_loc * 1024 + gbase + (size_t)j * 32;
#pragma unroll
    for (int c = 0; c < 8; ++c) {
        float4 w;
        w.x = (4 * c + 0 <= j) ? av[4 * c + 0] : 0.f;
        w.y = (4 * c + 1 <= j) ? av[4 * c + 1] : 0.f;
        w.z = (4 * c + 2 <= j) ? av[4 * c + 2] : 0.f;
        w.w = (4 * c + 3 <= j) ? av[4 * c + 3] : 0.f;
        *reinterpret_cast<float4*>(&lrow[4 * c]) = w;
    }

    if (j == 0) out[(size_t)n_loc * 2048 + locS] = hl ? nm01[1] : nm01[0];
}

extern "C" void kernel_launch(void* const* d_in, const int* in_sizes, int n_in,
                              void* d_out, int out_size, void* d_ws, size_t ws_size,
                              hipStream_t stream) {
    const float* aug    = (const float*)d_in[0];
    const float* scales = (const float*)d_in[1];
    const float* nug    = (const float*)d_in[2];
    const float* frac   = (const float*)d_in[3];
    const int*   bidx   = (const int*)  d_in[4];
    const float* thq    = (const float*)d_in[5];
    const float* sigp   = (const float*)d_in[6];
    const float* lens   = (const float*)d_in[7];
    const int n_loc = in_sizes[1];

    const int nblk = (n_loc + 1) / 2;
    tmk_kernel<<<nblk, 64, 0, stream>>>(aug, scales, nug, frac, bidx, thq,
                                        sigp, lens, (float*)d_out, n_loc);
}

// Round 5
// 121.425 us; speedup vs baseline: 1.3722x; 1.3722x over previous
//
#include <hip/hip_runtime.h>
#include <math.h>

#define NSAMP 32
#define XSTR  36                  // LDS row stride in floats (16B-aligned rows: 144B)
#define SQRT3 1.7320508075688772f

typedef _Float16 half8  __attribute__((ext_vector_type(8)));
typedef float    f32x16 __attribute__((ext_vector_type(16)));

// whole-wave broadcast from lane L (compile-time) — VALU op, no LDS pipe
__device__ __forceinline__ float rdlane(float v, int l) {
    return __int_as_float(__builtin_amdgcn_readlane(__float_as_int(v), l));
}

template<int K, int JJ>
struct Upd {
    static __device__ __forceinline__ void run(float* av, float lik) {
        av[JJ] = fmaf(-lik, rdlane(lik, JJ), av[JJ]);   // A[i][jj] -= L[i][k]*L[jj][k]
        Upd<K, JJ + 1>::run(av, lik);
    }
};
template<int K>
struct Upd<K, NSAMP> { static __device__ __forceinline__ void run(float*, float) {} };

template<int K>
struct Chol {
    static __device__ __forceinline__ void run(float* av) {
        float lik = av[K] * __frsqrt_rn(rdlane(av[K], K));  // L[i][k], i>=k
        av[K] = lik;
        Upd<K, K + 1>::run(av, lik);
        Chol<K + 1>::run(av);
    }
};
template<>
struct Chol<NSAMP> { static __device__ __forceinline__ void run(float*) {} };

__global__ __launch_bounds__(256, 6) void tmk_kernel(
    const float* __restrict__ aug,     // (32, n_loc, 31)
    const float* __restrict__ scales,  // (n_loc)
    const float* __restrict__ nug,     // (n_loc)
    const float* __restrict__ frac,    // (1)
    const int*   __restrict__ bidx,    // (n_loc)
    const float* __restrict__ thq,     // (1)
    const float* __restrict__ sigp,    // (2)
    const float* __restrict__ lens,    // (1)
    float* __restrict__ out,
    int n_loc)
{
    // all LDS is wave-private -> no __syncthreads anywhere
    __shared__ __align__(16) float X[4][NSAMP][XSTR];
    __shared__ float SQ[4][NSAMP];

    const int tid  = threadIdx.x;
    const int w    = tid >> 6;        // wave index = which location of this block
    const int lane = tid & 63;
    const int j    = lane & 31;       // Gram column owned by this lane (== row j by symmetry)
    const int hl   = lane >> 5;       // k-slice half
    const int kb   = 8 * hl;

    const int loc0 = blockIdx.x * 4;
    int loc = loc0 + w; if (loc >= n_loc) loc = n_loc - 1;   // 30000%4==0: never clamps

    const size_t srow = (size_t)n_loc * 31;

    // ---- stage this wave's location coalesced into X[w] (raw, NaN-fixed) ----
    if (lane < 60) {
        const int s0 = lane / 30;           // 0,1
        const int k  = lane - s0 * 30;      // 0..29
        const float* p = aug + (size_t)s0 * srow + (size_t)loc * 31 + 1 + k;
        float* xp = &X[w][s0][k];
#pragma unroll
        for (int it = 0; it < 16; ++it) {   // s = 2*it + s0 covers 0..31
            float v = p[(size_t)(2 * it) * srow];
            v = (v != v) ? 0.0f : v;        // isnan -> 0
            xp[2 * it * XSTR] = v;          // ds_write offset immediate
        }
    }
    // zero-pad k=30,31 for all 32 rows
    X[w][lane >> 1][30 + (lane & 1)] = 0.0f;

    // ---- per-lane feature scales ----
    const float a_s   = -0.5f * __expf(thq[0]);
    const float invls = 1.0f / (__expf(lens[0]) * SQRT3);
    float sl[8], sh[8];
#pragma unroll
    for (int e = 0; e < 8; ++e) {
        sl[e] = __expf(a_s * (float)(kb + e + 1))  * invls;   // k = kb+e
        sh[e] = __expf(a_s * (float)(kb + e + 17)) * invls;   // k = 16+kb+e
    }

    // ---- frag load (row j, own k-slice) + scale + f16 convert + norm ----
    const float* xr = &X[w][j][0];
    float4 r0 = *reinterpret_cast<const float4*>(xr + kb);
    float4 r1 = *reinterpret_cast<const float4*>(xr + kb + 4);
    float4 r2 = *reinterpret_cast<const float4*>(xr + 16 + kb);
    float4 r3 = *reinterpret_cast<const float4*>(xr + 16 + kb + 4);
    float v0[8] = {r0.x, r0.y, r0.z, r0.w, r1.x, r1.y, r1.z, r1.w};
    float v1[8] = {r2.x, r2.y, r2.z, r2.w, r3.x, r3.y, r3.z, r3.w};

    half8 fLo, fHi;
    float s0a = 0.f, s1a = 0.f;
#pragma unroll
    for (int e = 0; e < 8; ++e) {
        float a = v0[e] * sl[e];
        s0a = fmaf(a, a, s0a);
        fLo[e] = (_Float16)a;
        float b = v1[e] * sh[e];
        s1a = fmaf(b, b, s1a);
        fHi[e] = (_Float16)b;
    }
    float sqp    = s0a + s1a;
    float sqfull = sqp + __shfl_xor(sqp, 32);   // |x_row_j|^2
    if (hl == 0) SQ[w][j] = sqfull;             // same-wave LDS: in-order, no barrier

    // ---- Gram: G = Xl * Xl^T (A-frag == B-frag) ----
    f32x16 C = {};
    C = __builtin_amdgcn_mfma_f32_32x32x16_f16(fLo, fLo, C, 0, 0, 0);
    C = __builtin_amdgcn_mfma_f32_32x32x16_f16(fHi, fHi, C, 0, 0, 0);

    // ---- per-location coefficient ----
    const float scl = scales[loc];
    const float nm  = nug[loc];
    const float sig  = __expf(sigp[0] + sigp[1] * __logf(scl));
    const float coef = frac[0] * sig * sig / nm;
    const bool  bz   = (bidx[loc] == 0);

    // ---- matern epilogue on C (col=j, row=(r&3)+8*(r>>2)+4*hl); store g; assemble row j ----
    float* gout = out + (size_t)loc * 1024;
    const float* sqb = &SQ[w][4 * hl];
    float av[32];
#pragma unroll
    for (int r = 0; r < 16; ++r) {
        const int row0 = (r & 3) + 8 * (r >> 2);
        const int i    = row0 + 4 * hl;
        const bool dia = (j == i);
        float sqi = sqb[row0];                         // ds_read b32 (broadcast per half)
        float d2  = fmaf(-2.0f, C[r], sqi + sqfull);
        d2 = dia ? 0.0f : fmaxf(d2, 0.0f);
        float s3d = __fsqrt_rn(3.0f * d2);
        float nl  = (1.0f + s3d) * __expf(-s3d);
        float dg  = dia ? 1.0f : 0.0f;
        float gv  = fmaf(coef, nl, dg);
        if (bz) gv = dg;
        gout[i * 32 + j] = gv;                         // 2x128B lines per instr

        // partner half holds G[row0+4*(1-hl)][j]; symmetry: av[] = row j of G
        float pg = __shfl_xor(gv, 32);
        av[row0]     = hl ? pg : gv;                   // compile-time indices
        av[row0 + 4] = hl ? gv : pg;
    }

    // ---- register Cholesky, readlane broadcasts (lanes 32..63 duplicate, harmless) ----
    Chol<0>::run(av);

    // ---- masked L row store ----
    if (lane < 32) {
        float* lrow = out + (size_t)n_loc * 1024 + (size_t)loc * 1024 + (size_t)j * 32;
#pragma unroll
        for (int c = 0; c < 8; ++c) {
            float4 wv;
            wv.x = (4 * c + 0 <= j) ? av[4 * c + 0] : 0.f;
            wv.y = (4 * c + 1 <= j) ? av[4 * c + 1] : 0.f;
            wv.z = (4 * c + 2 <= j) ? av[4 * c + 2] : 0.f;
            wv.w = (4 * c + 3 <= j) ? av[4 * c + 3] : 0.f;
            *reinterpret_cast<float4*>(&lrow[4 * c]) = wv;
        }
    }

    // ---- nug_mean passthrough ----
    if (tid < 4) {
        int lc = loc0 + tid; if (lc >= n_loc) lc = n_loc - 1;
        out[(size_t)n_loc * 2048 + lc] = nug[lc];
    }
}

extern "C" void kernel_launch(void* const* d_in, const int* in_sizes, int n_in,
                              void* d_out, int out_size, void* d_ws, size_t ws_size,
                              hipStream_t stream) {
    const float* aug    = (const float*)d_in[0];
    const float* scales = (const float*)d_in[1];
    const float* nug    = (const float*)d_in[2];
    const float* frac   = (const float*)d_in[3];
    const int*   bidx   = (const int*)  d_in[4];
    const float* thq    = (const float*)d_in[5];
    const float* sigp   = (const float*)d_in[6];
    const float* lens   = (const float*)d_in[7];
    const int n_loc = in_sizes[1];

    const int nblk = (n_loc + 3) / 4;
    tmk_kernel<<<nblk, 256, 0, stream>>>(aug, scales, nug, frac, bidx, thq,
                                         sigp, lens, (float*)d_out, n_loc);
}